// Round 3
// baseline (3013.958 us; speedup 1.0000x reference)
//
#include <hip/hip_runtime.h>

#define N_PTS 8192
#define M_PTS 2048
#define K_NN 16
#define IN_CH 64
#define G_CH 68
#define OUT_CH 128
#define KCAP 128

// Unfusable fp32 ops: inline asm cannot be FMA-contracted by the compiler.
__device__ __forceinline__ float subrn(float a, float b) {
    float r; asm("v_sub_f32 %0, %1, %2" : "=v"(r) : "v"(a), "v"(b)); return r;
}
__device__ __forceinline__ float mulrn(float a, float b) {
    float r; asm("v_mul_f32 %0, %1, %2" : "=v"(r) : "v"(a), "v"(b)); return r;
}
__device__ __forceinline__ float addrn(float a, float b) {
    float r; asm("v_add_f32 %0, %1, %2" : "=v"(r) : "v"(a), "v"(b)); return r;
}
// numpy-exact fp32 squared distance: ((dx*dx + dy*dy) + dz*dz), per-op rounding.
__device__ __forceinline__ float sqdist_rn(float ax, float ay, float az,
                                           float bx, float by, float bz) {
    float dx = subrn(ax, bx);
    float dy = subrn(ay, by);
    float dz = subrn(az, bz);
    return addrn(addrn(mulrn(dx, dx), mulrn(dy, dy)), mulrn(dz, dz));
}

// Packed 2xfp32 ops (VOP3P). Each half is a plain IEEE fp32 op -> numerics
// bit-identical to scalar. Subtraction as a + (-b) (exact sign flip).
typedef float v2f __attribute__((ext_vector_type(2)));
__device__ __forceinline__ v2f pk_add(v2f a, v2f b) {
    v2f r; asm("v_pk_add_f32 %0, %1, %2" : "=v"(r) : "v"(a), "v"(b)); return r;
}
__device__ __forceinline__ v2f pk_mul(v2f a, v2f b) {
    v2f r; asm("v_pk_mul_f32 %0, %1, %2" : "=v"(r) : "v"(a), "v"(b)); return r;
}

// ---- DPP helpers ----------------------------------------------------------
template <int CTRL>
__device__ __forceinline__ float movdpp_f(float x) {
    int r = __builtin_amdgcn_mov_dpp(__float_as_int(x), CTRL, 0xf, 0xf, true);
    return __int_as_float(r);
}
// 8-lane-group max (lane%8-aligned)
__device__ __forceinline__ float group8_max(float x) {
    x = fmaxf(x, movdpp_f<0xB1>(x));
    x = fmaxf(x, movdpp_f<0x4E>(x));
    x = fmaxf(x, movdpp_f<0x141>(x));
    return x;
}

// ---- combined (dist, pid) argmax DPP reduce -------------------------------
// Carries (d, p) through each stage; winner = max d, tie -> min p.
// Full stages: all lanes valid.
template <int CTRL>
__device__ __forceinline__ void dpp_argmax_full(float& d, unsigned int& p) {
    float pd = movdpp_f<CTRL>(d);
    unsigned int pp_ = (unsigned int)__builtin_amdgcn_mov_dpp((int)p, CTRL, 0xf, 0xf, true);
    bool t = (pd > d) || (pd == d && pp_ < p);
    d = t ? pd : d;
    p = t ? pp_ : p;
}
// Masked bcast stages: disabled lanes receive old=(0, 0xFFFFFFFF) which can
// never win (d >= 0; tie at d==0 loses on pid compare) -> safe no-op there.
template <int CTRL, int RM>
__device__ __forceinline__ void dpp_argmax_masked(float& d, unsigned int& p) {
    int pdi = __builtin_amdgcn_update_dpp(0, __float_as_int(d), CTRL, RM, 0xf, false);
    int ppi = __builtin_amdgcn_update_dpp(-1, (int)p, CTRL, RM, 0xf, false);
    float pd = __int_as_float(pdi);
    unsigned int pp_ = (unsigned int)ppi;
    bool t = (pd > d) || (pd == d && pp_ < p);
    d = t ? pd : d;
    p = t ? pp_ : p;
}

__device__ __forceinline__ unsigned long long umax64(unsigned long long a,
                                                     unsigned long long b) {
    return a > b ? a : b;
}

// ---------------------------------------------------------------------------
// Kernel 1: FPS. Serial 2047-iteration chain. Single barrier per iteration,
// NO atomics (round-1's u64 LDS atomicMax lowered to a CAS loop -> regressed):
//   per-lane candidate (bd, pid) -> combined 6-stage DPP argmax (tie -> min
//   pid) -> lane63 ds_write_b64 of key=(dist_bits<<32)|(~pid) to rv[i&1][wave]
//   -> ONE __syncthreads -> all threads read 8 keys (64B uniform, broadcast)
//   -> 7-op u64-max tree -> last.
// rv is double-buffered: write of slot p at iter i+1 is separated from its
// last read (iter i-1) by barrier i -> race-free.
// key max == max dist (d>=0 -> IEEE bits order-preserving), tie -> smallest
// point index == reference argmax-first semantics.
// ---------------------------------------------------------------------------
__global__ __launch_bounds__(512, 2) void fps_kernel(const float4* __restrict__ events4,
                                                     int* __restrict__ down_idx,
                                                     float4* __restrict__ out_de) {
    extern __shared__ char smem[];
    unsigned long long* rv = (unsigned long long*)smem;        // 2 x 8 u64 (128 B)
    int*    ssel = (int*)(smem + 128);                         // 2048 ints
    float4* spt  = (float4*)(smem + 128 + 4 * M_PTS);          // 8192 float4

    const int b = blockIdx.x;
    const int tid = threadIdx.x;
    const int wave = tid >> 6;
    const int lane = tid & 63;
    const float4* ev = events4 + (size_t)b * N_PTS;

    for (int i = tid; i < N_PTS; i += 512) spt[i] = ev[i];
    if (tid == 0) ssel[0] = 0;
    __syncthreads();

    v2f px[8], py[8], pz[8];
    float dist[16];
#pragma unroll
    for (int pp = 0; pp < 8; ++pp) {
        float4 f0 = spt[(2 * pp) * 512 + tid];
        float4 f1 = spt[(2 * pp + 1) * 512 + tid];
        px[pp] = (v2f){f0.x, f1.x};
        py[pp] = (v2f){f0.y, f1.y};
        pz[pp] = (v2f){f0.z, f1.z};
        dist[2 * pp] = 1e10f; dist[2 * pp + 1] = 1e10f;   // reference init
    }

    int last = 0;
    for (int i = 1; i < M_PTS; ++i) {
        float4 L = spt[last];                     // uniform ds_read_b128
        const float nlx = -L.x, nly = -L.y, nlz = -L.z;   // exact sign flips
        const v2f nx2 = (v2f){nlx, nlx};
        const v2f ny2 = (v2f){nly, nly};
        const v2f nz2 = (v2f){nlz, nlz};
#pragma unroll
        for (int pp = 0; pp < 8; ++pp) {
            v2f dx = pk_add(px[pp], nx2);         // == px - lx, exact
            v2f dy = pk_add(py[pp], ny2);
            v2f dz = pk_add(pz[pp], nz2);
            v2f s  = pk_add(pk_add(pk_mul(dx, dx), pk_mul(dy, dy)), pk_mul(dz, dz));
            dist[2 * pp]     = fminf(dist[2 * pp],     s.x);
            dist[2 * pp + 1] = fminf(dist[2 * pp + 1], s.y);
        }
        float t0[8];
#pragma unroll
        for (int j = 0; j < 8; ++j) t0[j] = fmaxf(dist[2 * j], dist[2 * j + 1]);
#pragma unroll
        for (int j = 0; j < 4; ++j) t0[j] = fmaxf(t0[2 * j], t0[2 * j + 1]);
        float bd = fmaxf(fmaxf(t0[0], t0[1]), fmaxf(t0[2], t0[3]));

        // per-thread candidate slot: smallest j with dist[j]==bd (always exists)
        unsigned int jm = 0;
#pragma unroll
        for (int j = 15; j >= 0; --j) if (dist[j] == bd) jm = (unsigned int)j;
        unsigned int pid = jm * 512u + (unsigned int)tid;

        // combined wave argmax (max dist, tie -> min pid) -> lane 63
        float rd = bd; unsigned int rp_ = pid;
        dpp_argmax_full<0xB1>(rd, rp_);            // quad_perm xor1
        dpp_argmax_full<0x4E>(rd, rp_);            // quad_perm xor2
        dpp_argmax_full<0x141>(rd, rp_);           // row_half_mirror
        dpp_argmax_full<0x140>(rd, rp_);           // row_mirror
        dpp_argmax_masked<0x142, 0xa>(rd, rp_);    // row_bcast15 -> rows 1,3
        dpp_argmax_masked<0x143, 0xc>(rd, rp_);    // row_bcast31 -> lane63 full

        if (lane == 63) {
            unsigned long long key =
                ((unsigned long long)__float_as_uint(rd) << 32)
              | (unsigned long long)(0xFFFFFFFFu - rp_);
            rv[((i & 1) << 3) + wave] = key;       // plain ds_write_b64
        }
        __syncthreads();                           // single barrier per iteration

        const ulonglong2* rpair = (const ulonglong2*)(rv + ((i & 1) << 3));
        ulonglong2 q0 = rpair[0], q1 = rpair[1], q2 = rpair[2], q3 = rpair[3];
        unsigned long long k0 = umax64(q0.x, q0.y);
        unsigned long long k1 = umax64(q1.x, q1.y);
        unsigned long long k2 = umax64(q2.x, q2.y);
        unsigned long long k3 = umax64(q3.x, q3.y);
        unsigned long long kk = umax64(umax64(k0, k1), umax64(k2, k3));
        last = (int)(0xFFFFFFFFu - (unsigned int)kk);
        if (tid == 0) ssel[i] = last;
    }
    __syncthreads();

    for (int i = tid; i < M_PTS; i += 512) {
        int s = ssel[i];
        down_idx[b * M_PTS + i] = s;
        out_de[(size_t)b * M_PTS + i] = spt[s];
    }
}

// ---------------------------------------------------------------------------
// Kernel 2: 16-NN, threshold algorithm with adjacent-pair LDS reads.
// ---------------------------------------------------------------------------
__global__ __launch_bounds__(256, 1) void knn_kernel(const float4* __restrict__ events4,
                                                     const int* __restrict__ down_idx,
                                                     int* __restrict__ knn_idx) {
    extern __shared__ char smem[];
    float2* sxy  = (float2*)smem;                    // 8192 float2 (64 KB)
    float*  sz   = (float*)(smem + N_PTS * 8);       // 8192 floats (32 KB)
    float*  cd   = sz + N_PTS;                       // 32*KCAP floats
    int*    ci   = (int*)(cd + 32 * KCAP);           // 32*KCAP ints
    int*    scnt = (int*)(ci + 32 * KCAP);           // 32 ints

    const int b    = blockIdx.x >> 6;
    const int qg   = blockIdx.x & 63;
    const int tid  = threadIdx.x;
    const int ql   = tid >> 3;
    const int part = tid & 7;

    const float4* ev = events4 + (size_t)b * N_PTS;
    for (int i = tid; i < N_PTS; i += 256) {
        float4 e = ev[i];
        sxy[i] = (float2){e.x, e.y}; sz[i] = e.z;
    }
    if (tid < 32) scnt[tid] = 0;
    __syncthreads();

    const int q  = qg * 32 + ql;
    const int qi = down_idx[b * M_PTS + q];
    const float2 qxy = sxy[qi];
    const float qx = qxy.x, qy = qxy.y, qz = sz[qi];

    const float4* sxy4 = (const float4*)sxy;
    const float2* sz2  = (const float2*)sz;

    // pass 1: branchless top-2 smallest per lane, 2 adjacent pts per iter
    float m1 = 1e30f, m2 = 1e30f;
    for (int i = 0; i < N_PTS / 16; ++i) {
        const int ph = i * 8 + part;              // pair index; pts 2ph, 2ph+1
        float4 xy = sxy4[ph];
        float2 zz = sz2[ph];
        float d0 = sqdist_rn(xy.x, xy.y, zz.x, qx, qy, qz);
        float d1 = sqdist_rn(xy.z, xy.w, zz.y, qx, qy, qz);
        float lo0 = fminf(m1, d0);
        m2 = fminf(m2, fmaxf(m1, d0));
        m1 = lo0;
        float lo1 = fminf(m1, d1);
        m2 = fminf(m2, fmaxf(m1, d1));
        m1 = lo1;
    }
    const float T = group8_max(m2);

    // pass 2: compact candidates (same paired reads)
    for (int i = 0; i < N_PTS / 16; ++i) {
        const int ph = i * 8 + part;
        float4 xy = sxy4[ph];
        float2 zz = sz2[ph];
        float d0 = sqdist_rn(xy.x, xy.y, zz.x, qx, qy, qz);
        float d1 = sqdist_rn(xy.z, xy.w, zz.y, qx, qy, qz);
        if (d0 <= T) {
            int pos = atomicAdd(&scnt[ql], 1);
            if (pos < KCAP) { cd[ql * KCAP + pos] = d0; ci[ql * KCAP + pos] = 2 * ph; }
        }
        if (d1 <= T) {
            int pos = atomicAdd(&scnt[ql], 1);
            if (pos < KCAP) { cd[ql * KCAP + pos] = d1; ci[ql * KCAP + pos] = 2 * ph + 1; }
        }
    }
    __syncthreads();

    if (part == 0) {
        float nd[16]; int ni[16];
#pragma unroll
        for (int j = 0; j < 16; ++j) { nd[j] = 1e30f; ni[j] = 0x7fffffff; }
        float wmax = 1e30f; int widx = 0x7fffffff; int wslot_ = 0;
        const int n = scnt[ql];
        const int lim = (n <= KCAP) ? n : 0;
        for (int t = 0; t < lim; ++t) {
            float d = cd[ql * KCAP + t];
            int   p = ci[ql * KCAP + t];
            if (d < wmax || (d == wmax && p < widx)) {
#pragma unroll
                for (int j = 0; j < 16; ++j) if (j == wslot_) { nd[j] = d; ni[j] = p; }
                float m_ = -1.0f; int mix_ = -1; int ms_ = 0;
#pragma unroll
                for (int j = 0; j < 16; ++j)
                    if (nd[j] > m_ || (nd[j] == m_ && ni[j] > mix_)) { m_ = nd[j]; mix_ = ni[j]; ms_ = j; }
                wmax = m_; widx = mix_; wslot_ = ms_;
            }
        }
        if (n > KCAP) {   // exact serial fallback (never expected)
            for (int p = 0; p < N_PTS; ++p) {
                float2 pxy = sxy[p];
                float d = sqdist_rn(pxy.x, pxy.y, sz[p], qx, qy, qz);
                if (d < wmax || (d == wmax && p < widx)) {
#pragma unroll
                    for (int j = 0; j < 16; ++j) if (j == wslot_) { nd[j] = d; ni[j] = p; }
                    float m_ = -1.0f; int mix_ = -1; int ms_ = 0;
#pragma unroll
                    for (int j = 0; j < 16; ++j)
                        if (nd[j] > m_ || (nd[j] == m_ && ni[j] > mix_)) { m_ = nd[j]; mix_ = ni[j]; ms_ = j; }
                    wmax = m_; widx = mix_; wslot_ = ms_;
                }
            }
        }
        int* out = knn_idx + ((size_t)(b * M_PTS + q)) * K_NN;
#pragma unroll
        for (int j = 0; j < 16; ++j) out[j] = ni[j];
    }
}

// ---------------------------------------------------------------------------
// Kernel 3: gather + per-query (16x68)@(68x128) matmul + bias. Thread =
// (d, query-slot); 2 queries staged per round; float4 staging.
// ---------------------------------------------------------------------------
__global__ __launch_bounds__(256, 2) void gmm_kernel(const float4* __restrict__ events4,
                                                     const float4* __restrict__ feat4,
                                                     const float* __restrict__ W,
                                                     const float* __restrict__ bias,
                                                     const int* __restrict__ knn_idx,
                                                     const float4* __restrict__ de4,
                                                     float* __restrict__ hmax_g,
                                                     float* __restrict__ hmin_g,
                                                     float* __restrict__ gsum,
                                                     float* __restrict__ gsq) {
    __shared__ __align__(16) float4 sg4[2 * 16 * 17];   // 2 queries x 16 k x 17
    __shared__ float scomb[2 * OUT_CH];

    const int b   = blockIdx.x >> 7;
    const int qg  = blockIdx.x & 127;
    const int tid = threadIdx.x;
    const int d   = tid & 127;
    const int qs  = tid >> 7;          // query slot 0/1

    float w[G_CH];
#pragma unroll
    for (int c = 0; c < G_CH; ++c) w[c] = W[c * OUT_CH + d];
    const float breg = bias[d];

    float ssum = 0.f, ssq = 0.f;

    for (int r = 0; r < 8; ++r) {
        const int base = b * M_PTS + qg * 16 + 2 * r;
        for (int j4 = tid; j4 < 2 * 16 * 17; j4 += 256) {
            int qq = j4 / 272;
            int rem = j4 - qq * 272;
            int k = rem / 17;
            int c4 = rem - k * 17;
            int nb = knn_idx[(base + qq) * K_NN + k];
            float4 v;
            if (c4 == 0) {
                float4 e = events4[(size_t)b * N_PTS + nb];
                float4 d0 = de4[base + qq];
                v = (float4){e.x - d0.x, e.y - d0.y, e.z - d0.z, e.w - d0.w};
            } else {
                v = feat4[((size_t)(b * N_PTS + nb)) * 16 + (c4 - 1)];
            }
            sg4[j4] = v;
        }
        __syncthreads();

        float hmax = -1e30f, hmin = 1e30f;
#pragma unroll
        for (int k = 0; k < 16; ++k) {
            float acc = breg;
#pragma unroll
            for (int c4 = 0; c4 < 17; ++c4) {
                float4 g = sg4[qs * 272 + k * 17 + c4];
                acc = fmaf(g.x, w[4 * c4 + 0], acc);
                acc = fmaf(g.y, w[4 * c4 + 1], acc);
                acc = fmaf(g.z, w[4 * c4 + 2], acc);
                acc = fmaf(g.w, w[4 * c4 + 3], acc);
            }
            hmax = fmaxf(hmax, acc);
            hmin = fminf(hmin, acc);
            ssum += acc;
            ssq = fmaf(acc, acc, ssq);
        }
        const size_t o = (size_t)(base + qs) * OUT_CH + d;
        hmax_g[o] = hmax;
        hmin_g[o] = hmin;
        __syncthreads();   // protect sg before next staging
    }

    if (qs == 1) { scomb[d] = ssum; scomb[OUT_CH + d] = ssq; }
    __syncthreads();
    if (qs == 0) {
        atomicAdd(&gsum[d], ssum + scomb[d]);
        atomicAdd(&gsq[d],  ssq  + scomb[OUT_CH + d]);
    }
}

// ---------------------------------------------------------------------------
// Kernel 4: BN affine + relu + max-over-k via hmax/hmin (affine monotone).
// ---------------------------------------------------------------------------
__global__ __launch_bounds__(256) void fin_kernel(const float* __restrict__ hmax_g,
                                                  const float* __restrict__ hmin_g,
                                                  const float* __restrict__ gsum,
                                                  const float* __restrict__ gsq,
                                                  const float* __restrict__ gamma,
                                                  const float* __restrict__ beta,
                                                  float* __restrict__ out) {
    const size_t e = (size_t)blockIdx.x * 256 + threadIdx.x;
    const int d = (int)(e & 127);
    const float inv_cnt = 1.0f / 131072.0f;
    float mu  = gsum[d] * inv_cnt;
    float var = gsq[d] * inv_cnt - mu * mu;
    float a   = gamma[d] * rsqrtf(var + 1e-5f);
    float sh  = fmaf(-mu, a, beta[d]);
    float hv  = (a >= 0.f) ? hmax_g[e] : hmin_g[e];
    float r   = fmaf(a, hv, sh);
    out[32768 + e] = r > 0.f ? r : 0.f;
}

// ---------------------------------------------------------------------------
extern "C" void kernel_launch(void* const* d_in, const int* in_sizes, int n_in,
                              void* d_out, int out_size, void* d_ws, size_t ws_size,
                              hipStream_t stream) {
    const float* events   = (const float*)d_in[0];
    const float* features = (const float*)d_in[1];
    const float* W        = (const float*)d_in[2];
    const float* bias     = (const float*)d_in[3];
    const float* gamma    = (const float*)d_in[4];
    const float* beta     = (const float*)d_in[5];
    float* out = (float*)d_out;
    char* ws = (char*)d_ws;

    int*   down_idx = (int*)ws;                          // 32768 B
    int*   knn_idx  = (int*)(ws + 32768);                // 524288 B
    float* gsum     = (float*)(ws + 32768 + 524288);     // 512 B
    float* gsq      = gsum + OUT_CH;                     // 512 B
    float* hmaxg    = (float*)(ws + 558080);             // 4 MB
    float* hming    = hmaxg + (size_t)4 * M_PTS * OUT_CH;// 4 MB

    (void)hipMemsetAsync(gsum, 0, 2 * OUT_CH * sizeof(float), stream);

    const size_t fps_lds = 128 + 4 * M_PTS + (size_t)N_PTS * sizeof(float4); // 139392
    fps_kernel<<<4, 512, fps_lds, stream>>>((const float4*)events, down_idx, (float4*)out);

    const size_t knn_lds = (size_t)N_PTS * 8 + (size_t)N_PTS * 4
                         + (size_t)32 * KCAP * 8 + 128;                      // 131200
    knn_kernel<<<256, 256, knn_lds, stream>>>((const float4*)events, down_idx, knn_idx);

    gmm_kernel<<<512, 256, 0, stream>>>((const float4*)events, (const float4*)features,
                                        W, bias, knn_idx, (const float4*)out,
                                        hmaxg, hming, gsum, gsq);

    fin_kernel<<<4096, 256, 0, stream>>>(hmaxg, hming, gsum, gsq, gamma, beta, out);
}

// Round 4
// 2387.650 us; speedup vs baseline: 1.2623x; 1.2623x over previous
//
#include <hip/hip_runtime.h>

#define N_PTS 8192
#define M_PTS 2048
#define K_NN 16
#define IN_CH 64
#define G_CH 68
#define OUT_CH 128
#define KCAP 128

// Unfusable fp32 ops: inline asm cannot be FMA-contracted by the compiler.
__device__ __forceinline__ float subrn(float a, float b) {
    float r; asm("v_sub_f32 %0, %1, %2" : "=v"(r) : "v"(a), "v"(b)); return r;
}
__device__ __forceinline__ float mulrn(float a, float b) {
    float r; asm("v_mul_f32 %0, %1, %2" : "=v"(r) : "v"(a), "v"(b)); return r;
}
__device__ __forceinline__ float addrn(float a, float b) {
    float r; asm("v_add_f32 %0, %1, %2" : "=v"(r) : "v"(a), "v"(b)); return r;
}
// numpy-exact fp32 squared distance: ((dx*dx + dy*dy) + dz*dz), per-op rounding.
__device__ __forceinline__ float sqdist_rn(float ax, float ay, float az,
                                           float bx, float by, float bz) {
    float dx = subrn(ax, bx);
    float dy = subrn(ay, by);
    float dz = subrn(az, bz);
    return addrn(addrn(mulrn(dx, dx), mulrn(dy, dy)), mulrn(dz, dz));
}

// Packed 2xfp32 ops (VOP3P). Each half is a plain IEEE fp32 op -> numerics
// bit-identical to scalar. Subtraction as a + (-b) (exact sign flip).
typedef float v2f __attribute__((ext_vector_type(2)));
__device__ __forceinline__ v2f pk_add(v2f a, v2f b) {
    v2f r; asm("v_pk_add_f32 %0, %1, %2" : "=v"(r) : "v"(a), "v"(b)); return r;
}
__device__ __forceinline__ v2f pk_mul(v2f a, v2f b) {
    v2f r; asm("v_pk_mul_f32 %0, %1, %2" : "=v"(r) : "v"(a), "v"(b)); return r;
}

// 3-input max, single VALU op (VOP3). Exact: max is associative/commutative,
// inputs are never NaN here (squared distances or 1e10 sentinel).
__device__ __forceinline__ float max3f(float a, float b, float c) {
    float r; asm("v_max3_f32 %0, %1, %2, %3" : "=v"(r) : "v"(a), "v"(b), "v"(c));
    return r;
}

// ---- DPP helpers ----------------------------------------------------------
template <int CTRL>
__device__ __forceinline__ float movdpp_f(float x) {
    int r = __builtin_amdgcn_mov_dpp(__float_as_int(x), CTRL, 0xf, 0xf, true);
    return __int_as_float(r);
}
// masked bcast stages for wave max: update_dpp old=0 (max with 0 safe, d>=0)
template <int CTRL, int RM>
__device__ __forceinline__ float dppmaxf_m(float x) {
    int r = __builtin_amdgcn_update_dpp(0, __float_as_int(x), CTRL, RM, 0xf, false);
    return fmaxf(x, __int_as_float(r));
}
// full 64-lane max -> valid in lane 63
__device__ __forceinline__ float wave_max64(float x) {
    x = fmaxf(x, movdpp_f<0xB1>(x));   // quad_perm xor1
    x = fmaxf(x, movdpp_f<0x4E>(x));   // quad_perm xor2
    x = fmaxf(x, movdpp_f<0x141>(x));  // row_half_mirror
    x = fmaxf(x, movdpp_f<0x140>(x));  // row_mirror
    x = dppmaxf_m<0x142, 0xa>(x);      // row_bcast15 -> rows 1,3
    x = dppmaxf_m<0x143, 0xc>(x);      // row_bcast31 -> lane63 full
    return x;
}
// 8-lane-group max (lane%8-aligned) — used by knn pass 1
__device__ __forceinline__ float group8_max(float x) {
    x = fmaxf(x, movdpp_f<0xB1>(x));
    x = fmaxf(x, movdpp_f<0x4E>(x));
    x = fmaxf(x, movdpp_f<0x141>(x));
    return x;
}

// ---------------------------------------------------------------------------
// Kernel 1: FPS. Serial 2047-iteration chain. Structure = verified 2029us
// two-barrier election (R1/R3 single-barrier variants both regressed ->
// barriers/LDS round-trips are absorbed by 8-wave slack; dependent VALU/DPP
// chains are the expensive resource). This revision shortens only the VALU
// chains: v_max3 trees for the 16->1 per-thread max and the post-B1 8-partial
// combine (replacing 3 DPP stages with 2 uniform b128 reads + 4 VALU ops).
// ---------------------------------------------------------------------------
__global__ __launch_bounds__(512, 2) void fps_kernel(const float4* __restrict__ events4,
                                                     int* __restrict__ down_idx,
                                                     float4* __restrict__ out_de) {
    extern __shared__ char smem[];
    float*  rv   = (float*)smem;                   // 8 floats: wave-max partials
    int*    wsl  = (int*)(smem + 32);              // 2 ints: winner slot (parity)
    int*    ssel = (int*)(smem + 64);              // 2048 ints
    float4* spt  = (float4*)(smem + 64 + 4 * M_PTS);

    const int b = blockIdx.x;
    const int tid = threadIdx.x;
    const int wave = tid >> 6;
    const int lane = tid & 63;
    const float4* ev = events4 + (size_t)b * N_PTS;

    for (int i = tid; i < N_PTS; i += 512) spt[i] = ev[i];
    if (tid == 0) { ssel[0] = 0; wsl[0] = 0x7fffffff; wsl[1] = 0x7fffffff; }
    __syncthreads();

    v2f px[8], py[8], pz[8];
    float dist[16];
#pragma unroll
    for (int pp = 0; pp < 8; ++pp) {
        float4 f0 = spt[(2 * pp) * 512 + tid];
        float4 f1 = spt[(2 * pp + 1) * 512 + tid];
        px[pp] = (v2f){f0.x, f1.x};
        py[pp] = (v2f){f0.y, f1.y};
        pz[pp] = (v2f){f0.z, f1.z};
        dist[2 * pp] = 1e10f; dist[2 * pp + 1] = 1e10f;   // reference init
    }

    int last = 0;
    for (int i = 1; i < M_PTS; ++i) {
        float4 L = spt[last];                     // uniform ds_read_b128
        const float nlx = -L.x, nly = -L.y, nlz = -L.z;   // exact sign flips
        const v2f nx2 = (v2f){nlx, nlx};
        const v2f ny2 = (v2f){nly, nly};
        const v2f nz2 = (v2f){nlz, nlz};
#pragma unroll
        for (int pp = 0; pp < 8; ++pp) {
            v2f dx = pk_add(px[pp], nx2);         // == px - lx, exact
            v2f dy = pk_add(py[pp], ny2);
            v2f dz = pk_add(pz[pp], nz2);
            v2f s  = pk_add(pk_add(pk_mul(dx, dx), pk_mul(dy, dy)), pk_mul(dz, dz));
            dist[2 * pp]     = fminf(dist[2 * pp],     s.x);
            dist[2 * pp + 1] = fminf(dist[2 * pp + 1], s.y);
        }
        // 16 -> 1 max via v_max3 tree: 8 ops, depth 3 (was 15 fmax, depth 4)
        float a0 = max3f(dist[0],  dist[1],  dist[2]);
        float a1 = max3f(dist[3],  dist[4],  dist[5]);
        float a2 = max3f(dist[6],  dist[7],  dist[8]);
        float a3 = max3f(dist[9],  dist[10], dist[11]);
        float a4 = max3f(dist[12], dist[13], dist[14]);
        float bd = fmaxf(max3f(a0, a1, a2), max3f(a3, a4, dist[15]));

        float wm = wave_max64(bd);
        if (lane == 63) rv[wave] = wm;
        __syncthreads();                          // B1

        // block max: 2 uniform b128 broadcast reads + 4-op max3 tree
        const float4 r0 = *(const float4*)rv;
        const float4 r1 = *(const float4*)(rv + 4);
        float bm = max3f(max3f(r0.x, r0.y, r0.z),
                         max3f(r0.w, r1.x, r1.y),
                         fmaxf(r1.z, r1.w));

        if (bd == bm) {
            int jm = 0;
#pragma unroll
            for (int j = 15; j >= 0; --j) if (dist[j] == bd) jm = j;
            atomicMin(&wsl[i & 1], jm * 512 + tid);
        }
        __syncthreads();                          // B2
        last = wsl[i & 1];
        if (tid == 0) { ssel[i] = last; wsl[(i + 1) & 1] = 0x7fffffff; }
    }
    __syncthreads();

    for (int i = tid; i < M_PTS; i += 512) {
        int s = ssel[i];
        down_idx[b * M_PTS + i] = s;
        out_de[(size_t)b * M_PTS + i] = spt[s];
    }
}

// ---------------------------------------------------------------------------
// Kernel 2: 16-NN, threshold algorithm with adjacent-pair LDS reads.
// ---------------------------------------------------------------------------
__global__ __launch_bounds__(256, 1) void knn_kernel(const float4* __restrict__ events4,
                                                     const int* __restrict__ down_idx,
                                                     int* __restrict__ knn_idx) {
    extern __shared__ char smem[];
    float2* sxy  = (float2*)smem;                    // 8192 float2 (64 KB)
    float*  sz   = (float*)(smem + N_PTS * 8);       // 8192 floats (32 KB)
    float*  cd   = sz + N_PTS;                       // 32*KCAP floats
    int*    ci   = (int*)(cd + 32 * KCAP);           // 32*KCAP ints
    int*    scnt = (int*)(ci + 32 * KCAP);           // 32 ints

    const int b    = blockIdx.x >> 6;
    const int qg   = blockIdx.x & 63;
    const int tid  = threadIdx.x;
    const int ql   = tid >> 3;
    const int part = tid & 7;

    const float4* ev = events4 + (size_t)b * N_PTS;
    for (int i = tid; i < N_PTS; i += 256) {
        float4 e = ev[i];
        sxy[i] = (float2){e.x, e.y}; sz[i] = e.z;
    }
    if (tid < 32) scnt[tid] = 0;
    __syncthreads();

    const int q  = qg * 32 + ql;
    const int qi = down_idx[b * M_PTS + q];
    const float2 qxy = sxy[qi];
    const float qx = qxy.x, qy = qxy.y, qz = sz[qi];

    const float4* sxy4 = (const float4*)sxy;
    const float2* sz2  = (const float2*)sz;

    // pass 1: branchless top-2 smallest per lane, 2 adjacent pts per iter
    float m1 = 1e30f, m2 = 1e30f;
    for (int i = 0; i < N_PTS / 16; ++i) {
        const int ph = i * 8 + part;              // pair index; pts 2ph, 2ph+1
        float4 xy = sxy4[ph];
        float2 zz = sz2[ph];
        float d0 = sqdist_rn(xy.x, xy.y, zz.x, qx, qy, qz);
        float d1 = sqdist_rn(xy.z, xy.w, zz.y, qx, qy, qz);
        float lo0 = fminf(m1, d0);
        m2 = fminf(m2, fmaxf(m1, d0));
        m1 = lo0;
        float lo1 = fminf(m1, d1);
        m2 = fminf(m2, fmaxf(m1, d1));
        m1 = lo1;
    }
    const float T = group8_max(m2);

    // pass 2: compact candidates (same paired reads)
    for (int i = 0; i < N_PTS / 16; ++i) {
        const int ph = i * 8 + part;
        float4 xy = sxy4[ph];
        float2 zz = sz2[ph];
        float d0 = sqdist_rn(xy.x, xy.y, zz.x, qx, qy, qz);
        float d1 = sqdist_rn(xy.z, xy.w, zz.y, qx, qy, qz);
        if (d0 <= T) {
            int pos = atomicAdd(&scnt[ql], 1);
            if (pos < KCAP) { cd[ql * KCAP + pos] = d0; ci[ql * KCAP + pos] = 2 * ph; }
        }
        if (d1 <= T) {
            int pos = atomicAdd(&scnt[ql], 1);
            if (pos < KCAP) { cd[ql * KCAP + pos] = d1; ci[ql * KCAP + pos] = 2 * ph + 1; }
        }
    }
    __syncthreads();

    if (part == 0) {
        float nd[16]; int ni[16];
#pragma unroll
        for (int j = 0; j < 16; ++j) { nd[j] = 1e30f; ni[j] = 0x7fffffff; }
        float wmax = 1e30f; int widx = 0x7fffffff; int wslot_ = 0;
        const int n = scnt[ql];
        const int lim = (n <= KCAP) ? n : 0;
        for (int t = 0; t < lim; ++t) {
            float d = cd[ql * KCAP + t];
            int   p = ci[ql * KCAP + t];
            if (d < wmax || (d == wmax && p < widx)) {
#pragma unroll
                for (int j = 0; j < 16; ++j) if (j == wslot_) { nd[j] = d; ni[j] = p; }
                float m_ = -1.0f; int mix_ = -1; int ms_ = 0;
#pragma unroll
                for (int j = 0; j < 16; ++j)
                    if (nd[j] > m_ || (nd[j] == m_ && ni[j] > mix_)) { m_ = nd[j]; mix_ = ni[j]; ms_ = j; }
                wmax = m_; widx = mix_; wslot_ = ms_;
            }
        }
        if (n > KCAP) {   // exact serial fallback (never expected)
            for (int p = 0; p < N_PTS; ++p) {
                float2 pxy = sxy[p];
                float d = sqdist_rn(pxy.x, pxy.y, sz[p], qx, qy, qz);
                if (d < wmax || (d == wmax && p < widx)) {
#pragma unroll
                    for (int j = 0; j < 16; ++j) if (j == wslot_) { nd[j] = d; ni[j] = p; }
                    float m_ = -1.0f; int mix_ = -1; int ms_ = 0;
#pragma unroll
                    for (int j = 0; j < 16; ++j)
                        if (nd[j] > m_ || (nd[j] == m_ && ni[j] > mix_)) { m_ = nd[j]; mix_ = ni[j]; ms_ = j; }
                    wmax = m_; widx = mix_; wslot_ = ms_;
                }
            }
        }
        int* out = knn_idx + ((size_t)(b * M_PTS + q)) * K_NN;
#pragma unroll
        for (int j = 0; j < 16; ++j) out[j] = ni[j];
    }
}

// ---------------------------------------------------------------------------
// Kernel 3: gather + per-query (16x68)@(68x128) matmul + bias. Thread =
// (d, query-slot); 2 queries staged per round; float4 staging.
// ---------------------------------------------------------------------------
__global__ __launch_bounds__(256, 2) void gmm_kernel(const float4* __restrict__ events4,
                                                     const float4* __restrict__ feat4,
                                                     const float* __restrict__ W,
                                                     const float* __restrict__ bias,
                                                     const int* __restrict__ knn_idx,
                                                     const float4* __restrict__ de4,
                                                     float* __restrict__ hmax_g,
                                                     float* __restrict__ hmin_g,
                                                     float* __restrict__ gsum,
                                                     float* __restrict__ gsq) {
    __shared__ __align__(16) float4 sg4[2 * 16 * 17];   // 2 queries x 16 k x 17
    __shared__ float scomb[2 * OUT_CH];

    const int b   = blockIdx.x >> 7;
    const int qg  = blockIdx.x & 127;
    const int tid = threadIdx.x;
    const int d   = tid & 127;
    const int qs  = tid >> 7;          // query slot 0/1

    float w[G_CH];
#pragma unroll
    for (int c = 0; c < G_CH; ++c) w[c] = W[c * OUT_CH + d];
    const float breg = bias[d];

    float ssum = 0.f, ssq = 0.f;

    for (int r = 0; r < 8; ++r) {
        const int base = b * M_PTS + qg * 16 + 2 * r;
        for (int j4 = tid; j4 < 2 * 16 * 17; j4 += 256) {
            int qq = j4 / 272;
            int rem = j4 - qq * 272;
            int k = rem / 17;
            int c4 = rem - k * 17;
            int nb = knn_idx[(base + qq) * K_NN + k];
            float4 v;
            if (c4 == 0) {
                float4 e = events4[(size_t)b * N_PTS + nb];
                float4 d0 = de4[base + qq];
                v = (float4){e.x - d0.x, e.y - d0.y, e.z - d0.z, e.w - d0.w};
            } else {
                v = feat4[((size_t)(b * N_PTS + nb)) * 16 + (c4 - 1)];
            }
            sg4[j4] = v;
        }
        __syncthreads();

        float hmax = -1e30f, hmin = 1e30f;
#pragma unroll
        for (int k = 0; k < 16; ++k) {
            float acc = breg;
#pragma unroll
            for (int c4 = 0; c4 < 17; ++c4) {
                float4 g = sg4[qs * 272 + k * 17 + c4];
                acc = fmaf(g.x, w[4 * c4 + 0], acc);
                acc = fmaf(g.y, w[4 * c4 + 1], acc);
                acc = fmaf(g.z, w[4 * c4 + 2], acc);
                acc = fmaf(g.w, w[4 * c4 + 3], acc);
            }
            hmax = fmaxf(hmax, acc);
            hmin = fminf(hmin, acc);
            ssum += acc;
            ssq = fmaf(acc, acc, ssq);
        }
        const size_t o = (size_t)(base + qs) * OUT_CH + d;
        hmax_g[o] = hmax;
        hmin_g[o] = hmin;
        __syncthreads();   // protect sg before next staging
    }

    if (qs == 1) { scomb[d] = ssum; scomb[OUT_CH + d] = ssq; }
    __syncthreads();
    if (qs == 0) {
        atomicAdd(&gsum[d], ssum + scomb[d]);
        atomicAdd(&gsq[d],  ssq  + scomb[OUT_CH + d]);
    }
}

// ---------------------------------------------------------------------------
// Kernel 4: BN affine + relu + max-over-k via hmax/hmin (affine monotone).
// ---------------------------------------------------------------------------
__global__ __launch_bounds__(256) void fin_kernel(const float* __restrict__ hmax_g,
                                                  const float* __restrict__ hmin_g,
                                                  const float* __restrict__ gsum,
                                                  const float* __restrict__ gsq,
                                                  const float* __restrict__ gamma,
                                                  const float* __restrict__ beta,
                                                  float* __restrict__ out) {
    const size_t e = (size_t)blockIdx.x * 256 + threadIdx.x;
    const int d = (int)(e & 127);
    const float inv_cnt = 1.0f / 131072.0f;
    float mu  = gsum[d] * inv_cnt;
    float var = gsq[d] * inv_cnt - mu * mu;
    float a   = gamma[d] * rsqrtf(var + 1e-5f);
    float sh  = fmaf(-mu, a, beta[d]);
    float hv  = (a >= 0.f) ? hmax_g[e] : hmin_g[e];
    float r   = fmaf(a, hv, sh);
    out[32768 + e] = r > 0.f ? r : 0.f;
}

// ---------------------------------------------------------------------------
extern "C" void kernel_launch(void* const* d_in, const int* in_sizes, int n_in,
                              void* d_out, int out_size, void* d_ws, size_t ws_size,
                              hipStream_t stream) {
    const float* events   = (const float*)d_in[0];
    const float* features = (const float*)d_in[1];
    const float* W        = (const float*)d_in[2];
    const float* bias     = (const float*)d_in[3];
    const float* gamma    = (const float*)d_in[4];
    const float* beta     = (const float*)d_in[5];
    float* out = (float*)d_out;
    char* ws = (char*)d_ws;

    int*   down_idx = (int*)ws;                          // 32768 B
    int*   knn_idx  = (int*)(ws + 32768);                // 524288 B
    float* gsum     = (float*)(ws + 32768 + 524288);     // 512 B
    float* gsq      = gsum + OUT_CH;                     // 512 B
    float* hmaxg    = (float*)(ws + 558080);             // 4 MB
    float* hming    = hmaxg + (size_t)4 * M_PTS * OUT_CH;// 4 MB

    (void)hipMemsetAsync(gsum, 0, 2 * OUT_CH * sizeof(float), stream);

    const size_t fps_lds = 64 + 4 * M_PTS + (size_t)N_PTS * sizeof(float4); // 139328
    fps_kernel<<<4, 512, fps_lds, stream>>>((const float4*)events, down_idx, (float4*)out);

    const size_t knn_lds = (size_t)N_PTS * 8 + (size_t)N_PTS * 4
                         + (size_t)32 * KCAP * 8 + 128;                      // 131200
    knn_kernel<<<256, 256, knn_lds, stream>>>((const float4*)events, down_idx, knn_idx);

    gmm_kernel<<<512, 256, 0, stream>>>((const float4*)events, (const float4*)features,
                                        W, bias, knn_idx, (const float4*)out,
                                        hmaxg, hming, gsum, gsq);

    fin_kernel<<<4096, 256, 0, stream>>>(hmaxg, hming, gsum, gsq, gamma, beta, out);
}